// Round 1
// baseline (97.981 us; speedup 1.0000x reference)
//
#include <hip/hip_runtime.h>

#define NPIX    76800      // 240*320
#define WIDTH   320
#define NS      9
#define NTOT    (NPIX*NS)  // 691200
#define VDIM    320

// output offsets (all float32 elements, concatenated in return order)
#define OFF_FV  0
#define OFF_FW  691200
#define OFF_RP  1382400
#define OFF_D   3456000
#define OFF_I   3532800
#define OFF_W8  20121600
#define OFF_C   25651200

__global__ __launch_bounds__(256) void extractor_kernel(
    const float* __restrict__ depth,
    const float* __restrict__ extr,      // 4x4 row-major
    const float* __restrict__ intr,      // 3x3 row-major
    const float* __restrict__ vol,       // 320^3
    const float* __restrict__ wvol,      // 320^3
    const float* __restrict__ origin,    // 3
    const float* __restrict__ resolution,// 1
    float* __restrict__ out)
{
    const int tid = blockIdx.x * blockDim.x + threadIdx.x;
    if (tid >= NTOT) return;
    const int p = tid / NS;
    const int s = tid - p * NS;

    const int row = p / WIDTH;          // xx (v)
    const int col = p - row * WIDTH;    // yy (u)

    const float z = depth[p];

    // --- 3x3 inverse of intrinsics (adjugate) ---
    const float a00=intr[0], a01=intr[1], a02=intr[2];
    const float a10=intr[3], a11=intr[4], a12=intr[5];
    const float a20=intr[6], a21=intr[7], a22=intr[8];
    const float det = a00*(a11*a22 - a12*a21)
                    - a01*(a10*a22 - a12*a20)
                    + a02*(a10*a21 - a11*a20);
    const float id = 1.0f / det;
    const float i00 = (a11*a22 - a12*a21)*id;
    const float i01 = (a02*a21 - a01*a22)*id;
    const float i02 = (a01*a12 - a02*a11)*id;
    const float i10 = (a12*a20 - a10*a22)*id;
    const float i11 = (a00*a22 - a02*a20)*id;
    const float i12 = (a02*a10 - a00*a12)*id;
    const float i20 = (a10*a21 - a11*a20)*id;
    const float i21 = (a01*a20 - a00*a21)*id;
    const float i22 = (a00*a11 - a01*a10)*id;

    // pts_p = (u*z, v*z, z)
    const float up = (float)col * z;
    const float vp = (float)row * z;
    const float pcx = i00*up + i01*vp + i02*z;
    const float pcy = i10*up + i11*vp + i12*z;
    const float pcz = i20*up + i21*vp + i22*z;

    // world coords = (E @ [pc,1])[:3]
    const float cwx = extr[0]*pcx + extr[1]*pcy + extr[2]*pcz  + extr[3];
    const float cwy = extr[4]*pcx + extr[5]*pcy + extr[6]*pcz  + extr[7];
    const float cwz = extr[8]*pcx + extr[9]*pcy + extr[10]*pcz + extr[11];

    const float ox = origin[0], oy = origin[1], oz = origin[2];
    const float res = resolution[0];

    // voxel coords
    const float cvx = (cwx - ox) / res;
    const float cvy = (cwy - oy) / res;
    const float cvz = (cwz - oz) / res;
    const float evx = (extr[3]  - ox) / res;
    const float evy = (extr[7]  - oy) / res;
    const float evz = (extr[11] - oz) / res;

    float dx = cvx - evx, dy = cvy - evy, dz = cvz - evz;
    const float nrm = sqrtf(dx*dx + dy*dy + dz*dz);
    const float dn  = fmaxf(nrm, 1e-12f);
    dx /= dn; dy /= dn; dz /= dn;

    const float offs = (float)(s - 4);   // offs in [-4,4]
    const float pt[3] = { cvx + offs*dx, cvy + offs*dy, cvz + offs*dz };

    // --- trilinear setup ---
    float alpha[3], nb[3], fidx[3];
    #pragma unroll
    for (int k = 0; k < 3; ++k) {
        const float f  = floorf(pt[k]);
        const float c  = f + 0.5f;
        const float df = c - pt[k];
        nb[k]    = (df > 0.0f) ? 1.0f : ((df < 0.0f) ? -1.0f : 0.0f);
        alpha[k] = fabsf(pt[k] - c);
        fidx[k]  = f;
    }

    float fv = 0.0f, fw = 0.0f;
    float indsbuf[24];
    float w8buf[8];

    #pragma unroll
    for (int c = 0; c < 8; ++c) {
        float wgt = 1.0f;
        bool valid = true;
        int ii[3];
        #pragma unroll
        for (int k = 0; k < 3; ++k) {
            const float bit = ((c >> (2 - k)) & 1) ? 1.0f : 0.0f;
            wgt *= (bit > 0.0f) ? alpha[k] : (1.0f - alpha[k]);
            const float fi = fidx[k] + bit * nb[k];
            valid = valid && (fi >= 0.0f) && (fi < (float)VDIM);
            const float fc = fminf(fmaxf(fi, 0.0f), (float)(VDIM - 1));
            ii[k] = (int)fc;
            indsbuf[c*3 + k] = (float)ii[k];
        }
        const int lin = (ii[0]*VDIM + ii[1])*VDIM + ii[2];
        const float v  = vol[lin];
        const float wv = wvol[lin];
        if (valid) { fv += v * wgt; fw += wv * wgt; }
        w8buf[c] = wgt;
    }

    // --- writes ---
    out[OFF_FV + tid] = fv;
    out[OFF_FW + tid] = fw;
    out[OFF_RP + tid*3 + 0] = pt[0];
    out[OFF_RP + tid*3 + 1] = pt[1];
    out[OFF_RP + tid*3 + 2] = pt[2];

    float4* ip = reinterpret_cast<float4*>(out + OFF_I + tid*24);
    #pragma unroll
    for (int q = 0; q < 6; ++q)
        ip[q] = make_float4(indsbuf[q*4+0], indsbuf[q*4+1], indsbuf[q*4+2], indsbuf[q*4+3]);

    float4* wp = reinterpret_cast<float4*>(out + OFF_W8 + tid*8);
    wp[0] = make_float4(w8buf[0], w8buf[1], w8buf[2], w8buf[3]);
    wp[1] = make_float4(w8buf[4], w8buf[5], w8buf[6], w8buf[7]);

    if (s == 0) {
        out[OFF_D + p] = z;
        out[OFF_C + p*3 + 0] = cwx;
        out[OFF_C + p*3 + 1] = cwy;
        out[OFF_C + p*3 + 2] = cwz;
    }
}

extern "C" void kernel_launch(void* const* d_in, const int* in_sizes, int n_in,
                              void* d_out, int out_size, void* d_ws, size_t ws_size,
                              hipStream_t stream) {
    const float* depth      = (const float*)d_in[0];
    const float* extr       = (const float*)d_in[1];
    const float* intr       = (const float*)d_in[2];
    const float* vol        = (const float*)d_in[3];
    const float* wvol       = (const float*)d_in[4];
    const float* origin     = (const float*)d_in[5];
    const float* resolution = (const float*)d_in[6];
    float* out = (float*)d_out;

    const int threads = 256;
    const int blocks  = (NTOT + threads - 1) / threads;
    extractor_kernel<<<blocks, threads, 0, stream>>>(
        depth, extr, intr, vol, wvol, origin, resolution, out);
}